// Round 7
// baseline (710.597 us; speedup 1.0000x reference)
//
#include <hip/hip_runtime.h>
#include <stdint.h>

typedef unsigned short ushort_t;
typedef __attribute__((ext_vector_type(8))) __bf16 bf16x8;
typedef __attribute__((ext_vector_type(16))) float f32x16;
typedef __attribute__((ext_vector_type(4))) uint32_t u32x4;
typedef __attribute__((ext_vector_type(4))) float float4_t;

#define GPTR(x) ((__attribute__((address_space(1))) void*)(x))
#define LPTR(x) ((__attribute__((address_space(3))) void*)(x))

// Layer-1 K split into 3 feature-thirds: T0/T1 = 838 feats, T2 = 837.
// Each third expands to <=7542 elems, padded to KT=7552 (=236*32).
// W1 row = [T0|T1|T2], stride LDW1 = 3*KT. A-buffer holds ONE third: [8192, KT].
#define M8   8192
#define KT   7552
#define NKT  236
#define LDW1 22656
#define O1   512
#define K2   4608
#define O2P  384

__device__ __forceinline__ ushort_t f2b(float f) {
  union { float f; uint32_t i; } v; v.f = f;
  uint32_t x = v.i;
  uint32_t r = (x + 0x7FFFu + ((x >> 16) & 1u)) >> 16;  // RNE; finite data only
  return (ushort_t)r;
}

__device__ __forceinline__ void spline_expand(float x, float* sil, float* b /*8*/) {
  *sil = x / (1.0f + __expf(-x));
  float g[12];
#pragma unroll
  for (int j = 0; j < 12; ++j) g[j] = (float)(j - 3) * 0.4f - 1.0f;
  float t[11];
#pragma unroll
  for (int j = 0; j < 11; ++j) t[j] = (x >= g[j] && x < g[j + 1]) ? 1.0f : 0.0f;
#pragma unroll
  for (int k = 1; k <= 3; ++k) {
#pragma unroll
    for (int j = 0; j + k < 11; ++j) {
      float i1 = 1.0f / (g[j + k] - g[j]);        // constant-folded after unroll
      float i2 = 1.0f / (g[j + k + 1] - g[j + 1]);
      t[j] = (x - g[j]) * i1 * t[j] + (g[j + k + 1] - x) * i2 * t[j + 1];
    }
  }
#pragma unroll
  for (int k = 0; k < 8; ++k) b[k] = t[k];
}

// Expand one feature-third of x into A1t [M8, KT]. grid (M8).
__global__ __launch_bounds__(256) void expand_third(
    const float* __restrict__ xin, ushort_t* __restrict__ A1t, int f0, int fcnt) {
  __shared__ __align__(16) ushort_t sb[KT];
  const int row = blockIdx.x, tid = threadIdx.x;
  for (int t = tid; t < (KT >> 1); t += 256) ((uint32_t*)sb)[t] = 0;
  __syncthreads();
  const float* xr = xin + (size_t)row * 2513 + f0;
#pragma unroll
  for (int j = 0; j < 1024; j += 256) {
    int fl = j + tid;
    if (fl < fcnt) {
      float sil, b[8];
      spline_expand(xr[fl], &sil, b);
      ushort_t* o = &sb[fl * 9];
      o[0] = f2b(sil);
#pragma unroll
      for (int k = 0; k < 8; ++k) o[1 + k] = f2b(b[k]);
    }
  }
  __syncthreads();
  u32x4* dst = (u32x4*)(A1t + (size_t)row * KT);
  const u32x4* src = (const u32x4*)sb;
  for (int t = tid; t < (KT >> 3); t += 256) dst[t] = src[t];
}

// Both layers' augmented weights. grid (512+384, 3).
__global__ __launch_bounds__(256) void prepw_all(
    const float* __restrict__ bw1, const float* __restrict__ sw1, const float* __restrict__ sc1,
    const float* __restrict__ bw2, const float* __restrict__ sw2, const float* __restrict__ sc2,
    ushort_t* __restrict__ W1, ushort_t* __restrict__ W2) {
  __shared__ __align__(16) ushort_t sb[KT];
  const int bx = blockIdx.x, c = blockIdx.y, tid = threadIdx.x;
  const float *bw, *sw, *sc;
  ushort_t* dst;
  int in_f, o, out_f, ce, f0, fcnt;
  if (bx < 512) {
    o = bx; out_f = 512; in_f = 2513;
    ce = KT; f0 = c * 838;
    fcnt = (c == 2) ? 837 : 838;
    dst = W1 + (size_t)o * LDW1 + c * KT;
    bw = bw1; sw = sw1; sc = sc1;
  } else {
    if (c > 0) return;
    o = bx - 512; out_f = 300; in_f = 512;
    ce = K2; f0 = 0; fcnt = 512;
    dst = W2 + (size_t)o * K2;
    bw = bw2; sw = sw2; sc = sc2;
  }
  for (int t = tid; t < (ce >> 1); t += 256) ((uint32_t*)sb)[t] = 0;
  __syncthreads();
  if (o < out_f) {
#pragma unroll
    for (int j = 0; j < 1024; j += 256) {
      int fl = j + tid;
      if (fl < fcnt) {
        size_t base = (size_t)o * in_f + f0 + fl;
        float s = sc[base];
        float4_t s0 = ((const float4_t*)(sw + base * 8))[0];
        float4_t s1 = ((const float4_t*)(sw + base * 8))[1];
        ushort_t* w = &sb[fl * 9];
        w[0] = f2b(bw[base]);
        w[1] = f2b(s0.x * s); w[2] = f2b(s0.y * s);
        w[3] = f2b(s0.z * s); w[4] = f2b(s0.w * s);
        w[5] = f2b(s1.x * s); w[6] = f2b(s1.y * s);
        w[7] = f2b(s1.z * s); w[8] = f2b(s1.w * s);
      }
    }
  }
  __syncthreads();
  u32x4* d4 = (u32x4*)dst;
  const u32x4* s4 = (const u32x4*)sb;
  for (int t = tid; t < (ce >> 3); t += 256) d4[t] = s4[t];
}

// Layer-1 GEMM pass, 32x32x16 MFMA: A [M8, KT], B = W1-third [512 rows, LDW1 stride].
// K-split S=3 -> P[s, M8, O1] fp32; accum=1 -> read-add. 128x128 tile, BK=32,
// 4 waves each 64x64 = 2x2 of 32x32 (8 MFMA/iter vs 16 for 16x16 shape).
__global__ __launch_bounds__(256) void gemm1_kernel(
    const ushort_t* __restrict__ A, const ushort_t* __restrict__ Bw,
    float* __restrict__ P, int accum) {
  __shared__ __align__(16) ushort_t As[128 * 32];
  __shared__ __align__(16) ushort_t Bs[128 * 32];
  const int tid = threadIdx.x;
  const int m0 = blockIdx.x * 128;
  const int n0 = blockIdx.y * 128;
  const int s = blockIdx.z;
  const int k0 = s * 79;
  int k1 = k0 + 79; if (k1 > NKT) k1 = NKT;
  const int lane = tid & 63;
  const int wv = tid >> 6;
  const int wm = wv & 1, wn = wv >> 1;
  const int l31 = lane & 31, lh = lane >> 5;

  f32x16 acc[2][2];
#pragma unroll
  for (int a = 0; a < 2; ++a)
#pragma unroll
    for (int b = 0; b < 2; ++b)
#pragma unroll
      for (int r = 0; r < 16; ++r) acc[a][b][r] = 0.0f;

  const int u0 = tid, u1 = tid + 256;
  const int rA0 = u0 >> 2, sA0 = u0 & 3;
  const int rA1 = u1 >> 2, sA1 = u1 & 3;
  const ushort_t* gA0 = A + (size_t)(m0 + rA0) * KT + sA0 * 8;
  const ushort_t* gA1 = A + (size_t)(m0 + rA1) * KT + sA1 * 8;
  const ushort_t* gB0 = Bw + (size_t)(n0 + rA0) * LDW1 + sA0 * 8;
  const ushort_t* gB1 = Bw + (size_t)(n0 + rA1) * LDW1 + sA1 * 8;
  ushort_t* lA0 = &As[u0 * 8];
  ushort_t* lA1 = &As[u1 * 8];
  ushort_t* lB0 = &Bs[u0 * 8];
  ushort_t* lB1 = &Bs[u1 * 8];

  for (int kk = k0; kk < k1; ++kk) {
    const int kb = kk << 5;
    __syncthreads();
    __builtin_amdgcn_global_load_lds(GPTR(gA0 + kb), LPTR(lA0), 16, 0, 0);
    __builtin_amdgcn_global_load_lds(GPTR(gA1 + kb), LPTR(lA1), 16, 0, 0);
    __builtin_amdgcn_global_load_lds(GPTR(gB0 + kb), LPTR(lB0), 16, 0, 0);
    __builtin_amdgcn_global_load_lds(GPTR(gB1 + kb), LPTR(lB1), 16, 0, 0);
    __syncthreads();
    // 32x32x16 fragments: lane holds X[r=lane&31][k = ks*16 + (lane>>5)*8 + j]
    bf16x8 aF[2][2], bF[2][2];
#pragma unroll
    for (int ti = 0; ti < 2; ++ti)
#pragma unroll
      for (int ks = 0; ks < 2; ++ks) {
        aF[ti][ks] = *(const bf16x8*)(&As[(wm * 64 + ti * 32 + l31) * 32 + ks * 16 + lh * 8]);
        bF[ti][ks] = *(const bf16x8*)(&Bs[(wn * 64 + ti * 32 + l31) * 32 + ks * 16 + lh * 8]);
      }
#pragma unroll
    for (int ks = 0; ks < 2; ++ks)
#pragma unroll
      for (int ti = 0; ti < 2; ++ti)
#pragma unroll
        for (int tj = 0; tj < 2; ++tj)
          acc[ti][tj] = __builtin_amdgcn_mfma_f32_32x32x16_bf16(aF[ti][ks], bF[tj][ks], acc[ti][tj], 0, 0, 0);
  }

  // C/D 32x32 layout: col = lane&31, row = (reg&3) + 8*(reg>>2) + 4*(lane>>5)
  float* Pp = P + (size_t)s * M8 * O1;
#pragma unroll
  for (int ti = 0; ti < 2; ++ti) {
#pragma unroll
    for (int tj = 0; tj < 2; ++tj) {
      const int gr0 = m0 + wm * 64 + ti * 32;
      const int gc = n0 + wn * 64 + tj * 32 + l31;
#pragma unroll
      for (int r = 0; r < 16; ++r) {
        const int row = (r & 3) + 8 * (r >> 2) + 4 * lh;
        size_t pi = (size_t)(gr0 + row) * O1 + gc;
        float v = acc[ti][tj][r];
        if (accum) v += Pp[pi];
        Pp[pi] = v;
      }
    }
  }
}

// Sum 3 layer-1 partial slices -> relu -> expand into A2 row (512 feats -> 4608).
__global__ __launch_bounds__(256) void reduce_expand_stage(
    const float* __restrict__ P, ushort_t* __restrict__ A2) {
  __shared__ __align__(16) ushort_t sb[K2];
  const int row = blockIdx.x, tid = threadIdx.x;
  const size_t total = (size_t)M8 * O1;
#pragma unroll
  for (int j = 0; j < 512; j += 256) {
    int f = j + tid;
    size_t idx = (size_t)row * O1 + f;
    float v = P[idx] + P[total + idx] + P[2 * total + idx];
    if (v < 0.0f) v = 0.0f;
    float sil, b[8];
    spline_expand(v, &sil, b);
    ushort_t* o = &sb[f * 9];
    o[0] = f2b(sil);
#pragma unroll
    for (int k = 0; k < 8; ++k) o[1 + k] = f2b(b[k]);
  }
  __syncthreads();
  u32x4* dst = (u32x4*)(A2 + (size_t)row * K2);
  const u32x4* src = (const u32x4*)sb;
  for (int t = tid; t < (K2 >> 3); t += 256) dst[t] = src[t];
}

// Layer-2 GEMM, 32x32x16 MFMA, 64x64 tile, full K (no split), direct fp32 out.
// grid (128, 5) = 640 blocks covers cols 0..319 (mask <300). 4 waves = 2x2 of 32x32.
__global__ __launch_bounds__(256) void gemm2_kernel(
    const ushort_t* __restrict__ A, const ushort_t* __restrict__ Bw,
    float* __restrict__ out) {
  __shared__ __align__(16) ushort_t As[64 * 32];
  __shared__ __align__(16) ushort_t Bs[64 * 32];
  const int tid = threadIdx.x;
  const int m0 = blockIdx.x * 64;
  const int n0 = blockIdx.y * 64;
  const int lane = tid & 63;
  const int wv = tid >> 6;
  const int wm = wv & 1, wn = wv >> 1;
  const int l31 = lane & 31, lh = lane >> 5;

  f32x16 acc;
#pragma unroll
  for (int r = 0; r < 16; ++r) acc[r] = 0.0f;
  f32x16 acc2;
#pragma unroll
  for (int r = 0; r < 16; ++r) acc2[r] = 0.0f;
  (void)acc2;

  const int rA = tid >> 2, sA = tid & 3;
  const ushort_t* gA = A + (size_t)(m0 + rA) * K2 + sA * 8;
  const ushort_t* gB = Bw + (size_t)(n0 + rA) * K2 + sA * 8;
  ushort_t* lA = &As[tid * 8];
  ushort_t* lB = &Bs[tid * 8];

  for (int kk = 0; kk < 144; ++kk) {
    const int kb = kk << 5;
    __syncthreads();
    __builtin_amdgcn_global_load_lds(GPTR(gA + kb), LPTR(lA), 16, 0, 0);
    __builtin_amdgcn_global_load_lds(GPTR(gB + kb), LPTR(lB), 16, 0, 0);
    __syncthreads();
    bf16x8 aF[2], bF[2];
#pragma unroll
    for (int ks = 0; ks < 2; ++ks) {
      aF[ks] = *(const bf16x8*)(&As[(wm * 32 + l31) * 32 + ks * 16 + lh * 8]);
      bF[ks] = *(const bf16x8*)(&Bs[(wn * 32 + l31) * 32 + ks * 16 + lh * 8]);
    }
#pragma unroll
    for (int ks = 0; ks < 2; ++ks)
      acc = __builtin_amdgcn_mfma_f32_32x32x16_bf16(aF[ks], bF[ks], acc, 0, 0, 0);
  }

  const int gc = n0 + wn * 32 + l31;
  if (gc < 300) {
    const int gr0 = m0 + wm * 32;
#pragma unroll
    for (int r = 0; r < 16; ++r) {
      const int row = (r & 3) + 8 * (r >> 2) + 4 * lh;
      out[(size_t)(gr0 + row) * 300 + gc] = acc[r];
    }
  }
}

static inline size_t alup(size_t x) { return (x + 255) & ~(size_t)255; }

extern "C" void kernel_launch(void* const* d_in, const int* in_sizes, int n_in,
                              void* d_out, int out_size, void* d_ws, size_t ws_size,
                              hipStream_t stream) {
  const float* fp  = (const float*)d_in[0];
  const float* bw1 = (const float*)d_in[1];
  const float* sw1 = (const float*)d_in[2];
  const float* sc1 = (const float*)d_in[3];
  const float* bw2 = (const float*)d_in[4];
  const float* sw2 = (const float*)d_in[5];
  const float* sc2 = (const float*)d_in[6];
  float* out = (float*)d_out;

  char* wp = (char*)d_ws;
  size_t off = 0;
  ushort_t* W1a = (ushort_t*)(wp + off); off += alup((size_t)O1 * LDW1 * 2);   // 23.2 MB
  ushort_t* W2a = (ushort_t*)(wp + off); off += alup((size_t)O2P * K2 * 2);    //  3.5 MB
  float*    P   = (float*)(wp + off);    off += alup((size_t)3 * M8 * O1 * 4); // 50.3 MB
  ushort_t* A2c = (ushort_t*)(wp + off); off += alup((size_t)M8 * K2 * 2);     // 75.5 MB
  ushort_t* A1t = (ushort_t*)(wp + off); off += alup((size_t)M8 * KT * 2);     // 123.7 MB
  // total 276.2 MB — known-safe (R6 ran at this size; ws in [300,355) MB)

  prepw_all<<<dim3(896, 3), 256, 0, stream>>>(bw1, sw1, sc1, bw2, sw2, sc2, W1a, W2a);

  // Layer 1: three feature-third passes, accumulating into 3 shared P slices.
  for (int p = 0; p < 3; ++p) {
    const int f0 = p * 838;
    const int fcnt = (p == 2) ? 837 : 838;
    expand_third<<<M8, 256, 0, stream>>>(fp, A1t, f0, fcnt);
    gemm1_kernel<<<dim3(M8 / 128, O1 / 128, 3), 256, 0, stream>>>(A1t, W1a + p * KT, P, p > 0 ? 1 : 0);
  }

  reduce_expand_stage<<<M8, 256, 0, stream>>>(P, A2c);
  gemm2_kernel<<<dim3(M8 / 64, 5), 256, 0, stream>>>(A2c, W2a, out);

  (void)in_sizes; (void)n_in; (void)out_size; (void)ws_size;
}